// Round 8
// baseline (234.606 us; speedup 1.0000x reference)
//
#include <hip/hip_runtime.h>
#include <stdint.h>

// CML1D: 15-step coupled map lattice, fp32, rows=2048, L=16384.
//   mapped = R*g*(1-g);  g' = c0*mapped[i-1] + c1*mapped[i] + c2*mapped[i+1] + BETA*d
//   (circular). out = clip(g, 1e-4, 1-1e-4) after 15 steps.
//
// R9b: identical to R9 (round-7 bench died to container infra, no signal;
//   same precedent as round 4 -> 5 where resubmission ran clean).
//   Persistent x high-occupancy x packed x prefetch (the R6+R8 union).
//   - R4..R8 post-mortem: dur invariant at 81-85us = hbm_bytes / 2.45 TB/s
//     across every structural variant; VALU floor ~25us, LDS ~20us, HBM at
//     achievable BW ~32us. Diagnosis: memory duty cycle ~40% (burst-load /
//     compute / burst-store convoys leave HBM idle during compute phases).
//   - Fix: combine the two halves that were only ever tested separately:
//       * persistent waves, 2048 blocks = 8 blocks/CU resident, no convoy;
//       * SEG=512 packed compute (R8, bit-identical math, ~46 VGPR < 64
//         so __launch_bounds__(256,8) gives 8 waves/SIMD);
//       * double-buffered LDS (2x576 floats/wave, 18432 B/block; 147KB/CU);
//       * 1-deep global_load_lds prefetch: every wave always has the next
//         segment's 3 DMA loads in flight under ~1500cy of compute;
//       * stores never drained: vmcnt(2) = 3 older DMAs done, 2 output
//         stores still flying.
//   - Packed stencil (validated R8): P[j]=(c[j],c[j+4]); 1-cell shift = 1-step
//     shift in j; seams via 2 DPP wave-shifts (validated R7). mh = (-p)*p+p
//     via neg_lo/neg_hi: single-rounded, bit-identical to scalar fmaf.

constexpr float Rc    = 3.9f;
constexpr float EPSc  = 0.3f;
constexpr float BETAc = 0.15f;
constexpr int   STEPS = 15;
constexpr int   L     = 16384;
constexpr int   CE    = 9;              // cells per lane (extended)
constexpr int   HALF  = 4;              // pair stride: P[j]=(c[j],c[j+HALF])
constexpr int   NP    = HALF + 1;       // 5 pairs (c[4] duplicated)
constexpr int   SEG   = 512;            // valid cells per wave
constexpr int   GHOST = 32;             // > 15 steps of edge contamination
constexpr int   EXT   = SEG + 2*GHOST;  // 576 = 64*CE
constexpr int   TPB   = 256;
constexpr int   WPB   = TPB / 64;       // 4 waves per block
constexpr int   SPR   = L / SEG;        // 32 segments per row
constexpr int   NBLK  = 2048;           // 8 blocks/CU resident
constexpr int   T     = 8;              // segments per wave: 65536/(2048*4)

// gfx9 DPP ctrl (HW-validated in R7/R8):
constexpr int DPP_WAVE_SHL1 = 0x130;    // lane i <- lane i+1
constexpr int DPP_WAVE_SHR1 = 0x138;    // lane i <- lane i-1

__device__ __forceinline__ float dpp_shr1(float x) {
    return __int_as_float(__builtin_amdgcn_update_dpp(
        0, __float_as_int(x), DPP_WAVE_SHR1, 0xf, 0xf, true));
}
__device__ __forceinline__ float dpp_shl1(float x) {
    return __int_as_float(__builtin_amdgcn_update_dpp(
        0, __float_as_int(x), DPP_WAVE_SHL1, 0xf, 0xf, true));
}

// VOP3P packed fp32 (HW-validated in R8: same absmax as scalar path).
__device__ __forceinline__ float2 pk_mul(float2 a, float2 b) {
    float2 d;
    asm("v_pk_mul_f32 %0, %1, %2" : "=v"(d) : "v"(a), "v"(b));
    return d;
}
__device__ __forceinline__ float2 pk_fma(float2 a, float2 b, float2 c) {
    float2 d;
    asm("v_pk_fma_f32 %0, %1, %2, %3" : "=v"(d) : "v"(a), "v"(b), "v"(c));
    return d;
}
__device__ __forceinline__ float2 pk_fma_na(float2 a, float2 b, float2 c) {
    float2 d;   // d = (-a)*b + c, both halves, single-rounded
    asm("v_pk_fma_f32 %0, %1, %2, %3 neg_lo:[1,0,0] neg_hi:[1,0,0]"
        : "=v"(d) : "v"(a), "v"(b), "v"(c));
    return d;
}

typedef const __attribute__((address_space(1))) float gfloat;
typedef __attribute__((address_space(3))) float lfloat;

__global__ __launch_bounds__(TPB, 8)   // 8 waves/EU -> VGPR capped at 64
void cml1d_kernel(const float* __restrict__ drive,
                  const float* __restrict__ K,
                  float* __restrict__ out) {
    __shared__ float lds[WPB][2][EXT];   // 4*2*576*4 = 18432 B

    const int lane = threadIdx.x & 63;
    const int wv   = threadIdx.x >> 6;
    const int gw0  = blockIdx.x * WPB + wv;   // segment id for t=0; +8192 per t

    const float K0 = K[0], K1 = K[1], K2 = K[2];
    const float A  = (1.0f - BETAc) * (1.0f - EPSc);
    const float B  = (1.0f - BETAc) * EPSc;
    const float d0 = Rc * (B * K0);
    const float d1 = Rc * (A + B * K1);
    const float d2 = Rc * (B * K2);
    const float2 D0 = make_float2(d0, d0);
    const float2 D1 = make_float2(d1, d1);
    const float2 D2 = make_float2(d2, d2);
    const float2 B2 = make_float2(BETAc, BETAc);

    // async DMA: one segment's extended window -> LDS buf (holds no VGPRs)
    auto prefetch = [&](int gw, float* buf) {
        const int row = gw >> 5, seg = gw & (SPR - 1);
        const float* base = drive + (size_t)row * L;
        const int wb = seg * SEG - GHOST;        // mult of 32 -> wrap f4-safe
        #pragma unroll
        for (int j = 0; j < 2; ++j) {            // dest: j*1024B + lane*16B
            int idx = (wb + j * 256 + lane * 4) & (L - 1);
            __builtin_amdgcn_global_load_lds((gfloat*)(base + idx),
                                             (lfloat*)(buf + j * 256), 16, 0, 0);
        }
        int idx = (wb + 512 + lane) & (L - 1);   // tail 64 floats, width 4
        __builtin_amdgcn_global_load_lds((gfloat*)(base + idx),
                                         (lfloat*)(buf + 512), 4, 0, 0);
    };

    float2 P[NP], BD[NP];
    auto unpack = [&](const float* buf) {        // stride-9: 2 lanes/bank, free
        #pragma unroll
        for (int j = 0; j < NP; ++j) {
            P[j]  = make_float2(buf[lane * CE + j], buf[lane * CE + j + HALF]);
            BD[j] = pk_mul(B2, P[j]);
            asm volatile("" : "+v"(P[j]), "+v"(BD[j]));   // pin in VGPRs
        }
    };

    // ---- prime the pipeline ----
    prefetch(gw0, &lds[wv][0][0]);
    asm volatile("s_waitcnt vmcnt(0)" ::: "memory");
    unpack(&lds[wv][0][0]);

    int cur = 0;
    #pragma unroll 1
    for (int t = 0; t < T; ++t) {
        // next segment's DMA into the other buffer; flies under compute
        if (t < T - 1)
            prefetch((t + 1) * (NBLK * WPB) + gw0, &lds[wv][cur ^ 1][0]);
        __builtin_amdgcn_sched_barrier(0);   // pin DMA issue before compute

        // ---- 15 steps, register-only, packed (bit-identical to R8) ----
        for (int s = 0; s < STEPS; ++s) {
            float2 MH[NP];
            #pragma unroll
            for (int j = 0; j < NP; ++j)
                MH[j] = pk_fma_na(P[j], P[j], P[j]);       // mh = p - p^2

            const float mleft  = dpp_shr1(MH[NP - 1].y);   // lane-1 mh[8] = mh[-1]
            const float mright = dpp_shl1(MH[0].x);        // lane+1 mh[0] = mh[9]
            const float2 MHm1_0 = make_float2(mleft, MH[HALF - 1].x);
            const float2 MHp1_T = make_float2(MH[1].y, mright);

            #pragma unroll
            for (int j = 0; j < NP; ++j) {
                float2 a = (j == 0)      ? MHm1_0 : MH[j - 1];
                float2 b = (j == NP - 1) ? MHp1_T : MH[j + 1];
                P[j] = pk_fma(D0, a, pk_fma(D1, MH[j], pk_fma(D2, b, BD[j])));
            }
        }

        // ---- pairs -> LDS buf[cur] (dead since unpack) -> clamped f4 stores --
        const int gw  = t * (NBLK * WPB) + gw0;
        const int row = gw >> 5, seg = gw & (SPR - 1);
        float* tb = &lds[wv][cur][0];
        __builtin_amdgcn_wave_barrier();
        #pragma unroll
        for (int j = 0; j < NP; ++j) {
            tb[lane * CE + j]        = P[j].x;
            tb[lane * CE + j + HALF] = P[j].y;   // c4 dup, bitwise equal
        }
        __builtin_amdgcn_wave_barrier();

        const float lo = 0.0001f;
        const float hi = 0.9999f;   // float(1.0 - 0.0001)
        float* op = out + (size_t)row * L + seg * SEG;
        #pragma unroll
        for (int j = 0; j < 2; ++j) {
            int f = j * 64 + lane;                   // 128 float4 = 512 floats
            float4 v = *reinterpret_cast<float4*>(&tb[GHOST + f * 4]);
            v.x = __builtin_amdgcn_fmed3f(v.x, lo, hi);
            v.y = __builtin_amdgcn_fmed3f(v.y, lo, hi);
            v.z = __builtin_amdgcn_fmed3f(v.z, lo, hi);
            v.w = __builtin_amdgcn_fmed3f(v.w, lo, hi);
            *reinterpret_cast<float4*>(op + f * 4) = v;
        }

        // ---- swap: wait the 3 older DMAs; the 2 stores stay in flight ----
        if (t < T - 1) {
            asm volatile("s_waitcnt vmcnt(2)" ::: "memory");
            unpack(&lds[wv][cur ^ 1][0]);
            cur ^= 1;
        }
    }
}

extern "C" void kernel_launch(void* const* d_in, const int* in_sizes, int n_in,
                              void* d_out, int out_size, void* d_ws, size_t ws_size,
                              hipStream_t stream) {
    const float* drive = (const float*)d_in[0];
    const float* K     = (const float*)d_in[1];
    float* out         = (float*)d_out;
    cml1d_kernel<<<dim3(NBLK), dim3(TPB), 0, stream>>>(drive, K, out);
}